// Round 1
// baseline (2112.010 us; speedup 1.0000x reference)
//
#include <hip/hip_runtime.h>

#define NN 100000
#define NE 1200000
#define ITERS 5

typedef __attribute__((ext_vector_type(8))) short short8;
typedef __attribute__((ext_vector_type(4))) float floatx4;
typedef unsigned short ushort_t;

__device__ inline ushort_t f2bf(float f){
  unsigned u = __float_as_uint(f);
  unsigned r = (u + 0x7fffu + ((u>>16)&1u)) >> 16;
  return (ushort_t)r;
}
__device__ inline float bf2f(ushort_t u){ return __uint_as_float(((unsigned)u)<<16); }

// ------------------------- prep: counting sort by dst -------------------------
__global__ void k_count(const int* __restrict__ dst, int* __restrict__ cnt){
  int e = blockIdx.x*256 + threadIdx.x;
  if (e < NE) atomicAdd(&cnt[dst[e]], 1);
}

__global__ void k_scan1(const int* __restrict__ cnt, int* __restrict__ bsum){
  __shared__ int s[256];
  int t = threadIdx.x; int i = blockIdx.x*256 + t;
  s[t] = (i < NN) ? cnt[i] : 0; __syncthreads();
  for (int off=128; off>0; off>>=1){ if (t<off) s[t]+=s[t+off]; __syncthreads(); }
  if (t==0) bsum[blockIdx.x] = s[0];
}

__global__ void k_scan2(int* bsum, int nb){
  __shared__ int s[512];
  int t = threadIdx.x;
  int v = (t<nb)? bsum[t] : 0;
  s[t]=v; __syncthreads();
  for (int off=1; off<512; off<<=1){
    int x = (t>=off)? s[t-off] : 0; __syncthreads();
    s[t]+=x; __syncthreads();
  }
  if (t<nb) bsum[t] = s[t]-v; // exclusive
}

__global__ void k_scan3(const int* __restrict__ cnt, const int* __restrict__ bsum, int* __restrict__ rowptr){
  __shared__ int s[256];
  int t=threadIdx.x; int i = blockIdx.x*256+t;
  int v = (i<NN)? cnt[i]:0;
  s[t]=v; __syncthreads();
  for (int off=1; off<256; off<<=1){
    int x = (t>=off)? s[t-off] : 0; __syncthreads();
    s[t] += x; __syncthreads();
  }
  if (i<NN) rowptr[i] = bsum[blockIdx.x] + s[t] - v;
  if (i==0) rowptr[NN] = NE;
}

__global__ void k_scatter(const int* __restrict__ src, const int* __restrict__ dst,
                          const float* __restrict__ ef,
                          const int* __restrict__ rowptr, int* __restrict__ fill,
                          int* __restrict__ eperm, int* __restrict__ srcs, int* __restrict__ dsts,
                          unsigned* __restrict__ efs){
  int e = blockIdx.x*256+threadIdx.x;
  if (e>=NE) return;
  int d = dst[e];
  int pos = rowptr[d] + atomicAdd(&fill[d],1);
  eperm[pos]=e; srcs[pos]=src[e]; dsts[pos]=d;
  float2 f = reinterpret_cast<const float2*>(ef)[e];
  efs[pos] = (unsigned)f2bf(f.x) | ((unsigned)f2bf(f.y)<<16);
}

// weights -> bf16 MFMA B-fragment order: t = ((ks*4+ct)*64+l)*8+j
// value = W[ks*32+(l>>4)*8+j][ct*16+(l&15)] (0 if k>=Ksrc), W row-major [K][64]
__global__ void k_wprep(const float* __restrict__ W, ushort_t* __restrict__ frag, int Ksrc, int total){
  int t = blockIdx.x*256+threadIdx.x;
  if (t>=total) return;
  int j = t&7, l=(t>>3)&63, ct=(t>>9)&3, ks=t>>11;
  int k = ks*32 + ((l>>4)<<3) + j;
  int col = ct*16 + (l&15);
  float v = (k<Ksrc)? W[k*64+col] : 0.f;
  frag[t] = f2bf(v);
}

__global__ void k_init(const float* __restrict__ nf, const float* __restrict__ W, const float* __restrict__ b,
                       ushort_t* __restrict__ hA, ushort_t* __restrict__ emb){
  int t = blockIdx.x*256+threadIdx.x;
  if (t >= NN*64) return;
  int n=t>>6, c=t&63;
  float a = b[c];
  a += nf[n*3+0]*W[0*64+c];
  a += nf[n*3+1]*W[1*64+c];
  a += nf[n*3+2]*W[2*64+c];
  emb[t] = f2bf(a);
  hA[t] = f2bf(fmaxf(a,0.f));
}

// ------------------------- edge message kernel -------------------------
// 64 sorted edges / block, 4 waves. x = [h[dst] | h[src] | ef | pad] K=160.
__launch_bounds__(256)
__global__ void k_edge(const ushort_t* __restrict__ h,
                       const int* __restrict__ srcs, const int* __restrict__ dsts,
                       const unsigned* __restrict__ efs,
                       const ushort_t* __restrict__ w1f, const ushort_t* __restrict__ w2f,
                       const float* __restrict__ b1, const float* __restrict__ b2,
                       ushort_t* __restrict__ m_s){
  __shared__ short xl[4*5*64*8];   // A-fragments, K=160
  __shared__ short hl[4*2*64*8];   // hidden A-fragments, K=64
  int p0 = blockIdx.x*64;
  int tid = threadIdx.x;

  for (int c = tid; c < 64*20; c += 256){
    int e = c/20, cc = c - e*20;
    int p = p0 + e;
    short8 v = {0,0,0,0,0,0,0,0};
    if (cc < 8){
      v = *reinterpret_cast<const short8*>(h + (size_t)dsts[p]*64 + cc*8);
    } else if (cc < 16){
      v = *reinterpret_cast<const short8*>(h + (size_t)srcs[p]*64 + (cc-8)*8);
    } else if (cc == 16){
      unsigned u = efs[p];
      v[0] = (short)(u & 0xffffu); v[1] = (short)(u >> 16);
    }
    int w = e>>4, r = e&15, ks = cc>>2, g = cc&3;
    *reinterpret_cast<short8*>(&xl[(((w*5+ks)*64 + g*16 + r)<<3)]) = v;
  }
  __syncthreads();

  int wv = tid>>6, lane = tid&63;
  int r0 = (lane>>4)*4;
  const short8* xw = reinterpret_cast<const short8*>(xl) + wv*5*64 + lane;
  const short8* w1 = reinterpret_cast<const short8*>(w1f) + lane;
  floatx4 acc[4];
  #pragma unroll
  for (int ct=0;ct<4;ct++){ float bb=b1[ct*16+(lane&15)]; acc[ct]=(floatx4){bb,bb,bb,bb}; }
  #pragma unroll
  for (int ks=0; ks<5; ks++){
    short8 a = xw[ks*64];
    #pragma unroll
    for (int ct=0;ct<4;ct++)
      acc[ct] = __builtin_amdgcn_mfma_f32_16x16x32_bf16(a, w1[(ks*4+ct)*64], acc[ct], 0,0,0);
  }
  // relu -> hidden fragments
  #pragma unroll
  for (int ct=0; ct<4; ct++){
    int colk = ct*16 + (lane&15);
    int ks2 = colk>>5, g2=(colk>>3)&3, j2=colk&7;
    #pragma unroll
    for (int j=0;j<4;j++)
      hl[(((wv*2+ks2)*64 + g2*16 + (r0+j))<<3) + j2] = (short)f2bf(fmaxf(acc[ct][j],0.f));
  }
  __syncthreads();

  const short8* hw = reinterpret_cast<const short8*>(hl) + wv*2*64 + lane;
  const short8* w2 = reinterpret_cast<const short8*>(w2f) + lane;
  floatx4 mac[4];
  #pragma unroll
  for (int ct=0;ct<4;ct++){ float bb=b2[ct*16+(lane&15)]; mac[ct]=(floatx4){bb,bb,bb,bb}; }
  #pragma unroll
  for (int ks=0; ks<2; ks++){
    short8 a = hw[ks*64];
    #pragma unroll
    for (int ct=0;ct<4;ct++)
      mac[ct] = __builtin_amdgcn_mfma_f32_16x16x32_bf16(a, w2[(ks*4+ct)*64], mac[ct], 0,0,0);
  }
  #pragma unroll
  for (int ct=0;ct<4;ct++){
    int col = ct*16+(lane&15);
    #pragma unroll
    for (int j=0;j<4;j++)
      m_s[(size_t)(p0 + wv*16 + r0 + j)*64 + col] = f2bf(mac[ct][j]);
  }
}

// ------------------------- node update kernel -------------------------
// 64 nodes / block. Aggregate CSR slice of m (atomic-free), build x=[std|mn|mx|mean|h] K=320.
__launch_bounds__(256)
__global__ void k_update(const ushort_t* __restrict__ m_s,
                         const int* __restrict__ rowptr,
                         const ushort_t* __restrict__ hin,
                         const ushort_t* __restrict__ w1f, const ushort_t* __restrict__ w2f,
                         const float* __restrict__ b1, const float* __restrict__ b2,
                         ushort_t* __restrict__ emb, ushort_t* __restrict__ hout){
  __shared__ short xl[4*10*64*8];  // K=320 fragments
  __shared__ short hl[4*2*64*8];
  int n0 = blockIdx.x*64;
  int tid = threadIdx.x;
  int c = tid&63, s = tid>>6;

  for (int ni=s; ni<64; ni+=4){
    int n = n0+ni;
    float sm=0.f, sq=0.f, mn=3.4e38f, mx=-3.4e38f;
    int deg=0; ushort_t hval=0;
    if (n<NN){
      int rp0=rowptr[n], rp1=rowptr[n+1]; deg = rp1-rp0;
      for (int p=rp0;p<rp1;p++){
        float v = bf2f(m_s[(size_t)p*64+c]);
        sm+=v; sq+=v*v; mn=fminf(mn,v); mx=fmaxf(mx,v);
      }
      hval = hin[(size_t)n*64+c];
    }
    float cc_ = (float)(deg>0?deg:1);
    float mean = sm/cc_;
    float var = fmaxf(sq/cc_ - mean*mean, 0.f);
    float sd = __fsqrt_rn(var + 1e-5f);
    if (deg==0){ mn=0.f; mx=0.f; }
    if (n>=NN){ sd=0.f; mn=0.f; mx=0.f; mean=0.f; hval=0; }
    int w=ni>>4, r=ni&15;
    ushort_t vals[5] = { f2bf(sd), f2bf(mn), f2bf(mx), f2bf(mean), hval };
    #pragma unroll
    for (int q=0;q<5;q++){
      int k = q*64 + c;
      int ks=k>>5, g=(k>>3)&3, j=k&7;
      xl[(((w*10+ks)*64 + g*16 + r)<<3) + j] = (short)vals[q];
    }
  }
  __syncthreads();

  int wv = tid>>6, lane = tid&63;
  int r0 = (lane>>4)*4;
  const short8* xw = reinterpret_cast<const short8*>(xl) + wv*10*64 + lane;
  const short8* w1 = reinterpret_cast<const short8*>(w1f) + lane;
  floatx4 acc[4];
  #pragma unroll
  for (int ct=0;ct<4;ct++){ float bb=b1[ct*16+(lane&15)]; acc[ct]=(floatx4){bb,bb,bb,bb}; }
  #pragma unroll
  for (int ks=0; ks<10; ks++){
    short8 a = xw[ks*64];
    #pragma unroll
    for (int ct=0;ct<4;ct++)
      acc[ct] = __builtin_amdgcn_mfma_f32_16x16x32_bf16(a, w1[(ks*4+ct)*64], acc[ct], 0,0,0);
  }
  #pragma unroll
  for (int ct=0; ct<4; ct++){
    int colk = ct*16 + (lane&15);
    int ks2 = colk>>5, g2=(colk>>3)&3, j2=colk&7;
    #pragma unroll
    for (int j=0;j<4;j++)
      hl[(((wv*2+ks2)*64 + g2*16 + (r0+j))<<3) + j2] = (short)f2bf(fmaxf(acc[ct][j],0.f));
  }
  __syncthreads();

  const short8* hw = reinterpret_cast<const short8*>(hl) + wv*2*64 + lane;
  const short8* w2 = reinterpret_cast<const short8*>(w2f) + lane;
  floatx4 mac[4];
  #pragma unroll
  for (int ct=0;ct<4;ct++){ float bb=b2[ct*16+(lane&15)]; mac[ct]=(floatx4){bb,bb,bb,bb}; }
  #pragma unroll
  for (int ks=0; ks<2; ks++){
    short8 a = hw[ks*64];
    #pragma unroll
    for (int ct=0;ct<4;ct++)
      mac[ct] = __builtin_amdgcn_mfma_f32_16x16x32_bf16(a, w2[(ks*4+ct)*64], mac[ct], 0,0,0);
  }
  #pragma unroll
  for (int ct=0;ct<4;ct++){
    int col = ct*16+(lane&15);
    #pragma unroll
    for (int j=0;j<4;j++){
      int n = n0 + wv*16 + r0 + j;
      if (n < NN){
        float v = mac[ct][j];
        emb[(size_t)n*64+col] = f2bf(v);
        hout[(size_t)n*64+col] = f2bf(fmaxf(v,0.f));
      }
    }
  }
}

// ------------------------- readout kernel -------------------------
// x = [emb[src] | emb[dst] | ef | pad], layer2 is 64-dot -> scalar.
__launch_bounds__(256)
__global__ void k_readout(const ushort_t* __restrict__ emb,
                          const int* __restrict__ srcs, const int* __restrict__ dsts,
                          const unsigned* __restrict__ efs, const int* __restrict__ eperm,
                          const ushort_t* __restrict__ w1f,
                          const float* __restrict__ b1,
                          const float* __restrict__ w2, const float* __restrict__ b2,
                          float* __restrict__ out){
  __shared__ short xl[4*5*64*8];
  int p0 = blockIdx.x*64;
  int tid = threadIdx.x;

  for (int c = tid; c < 64*20; c += 256){
    int e = c/20, cc = c - e*20;
    int p = p0 + e;
    short8 v = {0,0,0,0,0,0,0,0};
    if (cc < 8){
      v = *reinterpret_cast<const short8*>(emb + (size_t)srcs[p]*64 + cc*8);   // attacker = src first
    } else if (cc < 16){
      v = *reinterpret_cast<const short8*>(emb + (size_t)dsts[p]*64 + (cc-8)*8);
    } else if (cc == 16){
      unsigned u = efs[p];
      v[0] = (short)(u & 0xffffu); v[1] = (short)(u >> 16);
    }
    int w = e>>4, r = e&15, ks = cc>>2, g = cc&3;
    *reinterpret_cast<short8*>(&xl[(((w*5+ks)*64 + g*16 + r)<<3)]) = v;
  }
  __syncthreads();

  int wv = tid>>6, lane = tid&63;
  int r0 = (lane>>4)*4;
  const short8* xw = reinterpret_cast<const short8*>(xl) + wv*5*64 + lane;
  const short8* w1 = reinterpret_cast<const short8*>(w1f) + lane;
  floatx4 acc[4];
  #pragma unroll
  for (int ct=0;ct<4;ct++){ float bb=b1[ct*16+(lane&15)]; acc[ct]=(floatx4){bb,bb,bb,bb}; }
  #pragma unroll
  for (int ks=0; ks<5; ks++){
    short8 a = xw[ks*64];
    #pragma unroll
    for (int ct=0;ct<4;ct++)
      acc[ct] = __builtin_amdgcn_mfma_f32_16x16x32_bf16(a, w1[(ks*4+ct)*64], acc[ct], 0,0,0);
  }
  float w2v[4];
  #pragma unroll
  for (int ct=0;ct<4;ct++) w2v[ct] = w2[ct*16+(lane&15)];
  float part[4];
  #pragma unroll
  for (int j=0;j<4;j++){
    float pj = 0.f;
    #pragma unroll
    for (int ct=0;ct<4;ct++) pj += fmaxf(acc[ct][j],0.f)*w2v[ct];
    part[j] = pj;
  }
  #pragma unroll
  for (int m=1;m<16;m<<=1){
    #pragma unroll
    for (int j=0;j<4;j++) part[j] += __shfl_xor(part[j], m, 64);
  }
  if ((lane&15)==0){
    float bb = b2[0];
    #pragma unroll
    for (int j=0;j<4;j++)
      out[eperm[p0 + wv*16 + r0 + j]] = part[j] + bb;
  }
}

// ------------------------- launcher -------------------------
extern "C" void kernel_launch(void* const* d_in, const int* in_sizes, int n_in,
                              void* d_out, int out_size, void* d_ws, size_t ws_size,
                              hipStream_t stream){
  const float* nf    = (const float*)d_in[0];
  const float* ef    = (const float*)d_in[1];
  const float* initW = (const float*)d_in[2];
  const float* initb = (const float*)d_in[3];
  const float* msgW1 = (const float*)d_in[4];
  const float* msgb1 = (const float*)d_in[5];
  const float* msgW2 = (const float*)d_in[6];
  const float* msgb2 = (const float*)d_in[7];
  const float* updW1 = (const float*)d_in[8];
  const float* updb1 = (const float*)d_in[9];
  const float* updW2 = (const float*)d_in[10];
  const float* updb2 = (const float*)d_in[11];
  const float* roW1  = (const float*)d_in[12];
  const float* rob1  = (const float*)d_in[13];
  const float* roW2  = (const float*)d_in[14];
  const float* rob2  = (const float*)d_in[15];
  const int*   eidx  = (const int*)d_in[16];
  const int* srcI = eidx;
  const int* dstI = eidx + NE;
  float* out = (float*)d_out;

  char* base = (char*)d_ws; size_t off = 0;
  auto alloc = [&](size_t b)->char*{ char* p = base + off; off = (off + b + 255) & ~(size_t)255; return p; };
  int* cnt    = (int*)alloc((size_t)NN*4);
  int* fill   = (int*)alloc((size_t)NN*4);
  int* rowptr = (int*)alloc((size_t)(NN+1)*4);
  int* bsum   = (int*)alloc(512*4);
  int* eperm  = (int*)alloc((size_t)NE*4);
  int* srcs   = (int*)alloc((size_t)NE*4);
  int* dsts   = (int*)alloc((size_t)NE*4);
  unsigned* efs = (unsigned*)alloc((size_t)NE*4);
  ushort_t* hA  = (ushort_t*)alloc((size_t)NN*64*2);
  ushort_t* hB  = (ushort_t*)alloc((size_t)NN*64*2);
  ushort_t* emb = (ushort_t*)alloc((size_t)NN*64*2);
  ushort_t* m_s = (ushort_t*)alloc((size_t)NE*64*2);
  ushort_t* msgW1f = (ushort_t*)alloc(5*2048*2);
  ushort_t* msgW2f = (ushort_t*)alloc(2*2048*2);
  ushort_t* updW1f = (ushort_t*)alloc(10*2048*2);
  ushort_t* updW2f = (ushort_t*)alloc(2*2048*2);
  ushort_t* roW1f  = (ushort_t*)alloc(5*2048*2);
  (void)ws_size; (void)in_sizes; (void)n_in; (void)out_size;

  hipMemsetAsync(cnt, 0, (size_t)NN*4, stream);
  hipMemsetAsync(fill, 0, (size_t)NN*4, stream);
  int nb = (NN+255)/256;
  k_count<<<(NE+255)/256,256,0,stream>>>(dstI,cnt);
  k_scan1<<<nb,256,0,stream>>>(cnt,bsum);
  k_scan2<<<1,512,0,stream>>>(bsum,nb);
  k_scan3<<<nb,256,0,stream>>>(cnt,bsum,rowptr);
  k_scatter<<<(NE+255)/256,256,0,stream>>>(srcI,dstI,ef,rowptr,fill,eperm,srcs,dsts,efs);
  k_wprep<<<(5*2048+255)/256,256,0,stream>>>(msgW1,msgW1f,130,5*2048);
  k_wprep<<<(2*2048+255)/256,256,0,stream>>>(msgW2,msgW2f,64,2*2048);
  k_wprep<<<(10*2048+255)/256,256,0,stream>>>(updW1,updW1f,320,10*2048);
  k_wprep<<<(2*2048+255)/256,256,0,stream>>>(updW2,updW2f,64,2*2048);
  k_wprep<<<(5*2048+255)/256,256,0,stream>>>(roW1,roW1f,130,5*2048);
  k_init<<<(NN*64+255)/256,256,0,stream>>>(nf,initW,initb,hA,emb);

  for (int it=0; it<ITERS; it++){
    const ushort_t* hin = (it&1)? hB : hA;
    ushort_t* hout      = (it&1)? hA : hB;
    k_edge<<<NE/64,256,0,stream>>>(hin,srcs,dsts,efs,msgW1f,msgW2f,msgb1,msgb2,m_s);
    k_update<<<(NN+63)/64,256,0,stream>>>(m_s,rowptr,hin,updW1f,updW2f,updb1,updb2,emb,hout);
  }
  k_readout<<<NE/64,256,0,stream>>>(emb,srcs,dsts,efs,eperm,roW1f,rob1,roW2,rob2,out);
}

// Round 4
// 1391.200 us; speedup vs baseline: 1.5181x; 1.5181x over previous
//
#include <hip/hip_runtime.h>

#define NN 100000
#define NE 1200000
#define ITERS 5

typedef __attribute__((ext_vector_type(8))) short short8;
typedef __attribute__((ext_vector_type(4))) short short4_t;
typedef __attribute__((ext_vector_type(4))) float floatx4;
typedef unsigned short ushort_t;

__device__ inline ushort_t f2bf(float f){
  unsigned u = __float_as_uint(f);
  unsigned r = (u + 0x7fffu + ((u>>16)&1u)) >> 16;
  return (ushort_t)r;
}
__device__ inline float bf2f(ushort_t u){ return __uint_as_float(((unsigned)u)<<16); }
__device__ inline float bf2f_lo(unsigned u){ return __uint_as_float(u<<16); }
__device__ inline float bf2f_hi(unsigned u){ return __uint_as_float(u & 0xffff0000u); }

// ------------------------- prep: counting sort by dst -------------------------
__global__ void k_count(const int* __restrict__ dst, int* __restrict__ cnt){
  int e = blockIdx.x*256 + threadIdx.x;
  if (e < NE) atomicAdd(&cnt[dst[e]], 1);
}

__global__ void k_scan1(const int* __restrict__ cnt, int* __restrict__ bsum){
  __shared__ int s[256];
  int t = threadIdx.x; int i = blockIdx.x*256 + t;
  s[t] = (i < NN) ? cnt[i] : 0; __syncthreads();
  for (int off=128; off>0; off>>=1){ if (t<off) s[t]+=s[t+off]; __syncthreads(); }
  if (t==0) bsum[blockIdx.x] = s[0];
}

__global__ void k_scan2(int* bsum, int nb){
  __shared__ int s[512];
  int t = threadIdx.x;
  int v = (t<nb)? bsum[t] : 0;
  s[t]=v; __syncthreads();
  for (int off=1; off<512; off<<=1){
    int x = (t>=off)? s[t-off] : 0; __syncthreads();
    s[t]+=x; __syncthreads();
  }
  if (t<nb) bsum[t] = s[t]-v; // exclusive
}

__global__ void k_scan3(const int* __restrict__ cnt, const int* __restrict__ bsum, int* __restrict__ rowptr){
  __shared__ int s[256];
  int t=threadIdx.x; int i = blockIdx.x*256+t;
  int v = (i<NN)? cnt[i]:0;
  s[t]=v; __syncthreads();
  for (int off=1; off<256; off<<=1){
    int x = (t>=off)? s[t-off] : 0; __syncthreads();
    s[t] += x; __syncthreads();
  }
  if (i<NN) rowptr[i] = bsum[blockIdx.x] + s[t] - v;
  if (i==0) rowptr[NN] = NE;
}

__global__ void k_scatter(const int* __restrict__ src, const int* __restrict__ dst,
                          const float* __restrict__ ef,
                          const int* __restrict__ rowptr, int* __restrict__ fill,
                          int* __restrict__ eperm, int* __restrict__ srcs, int* __restrict__ dsts,
                          unsigned* __restrict__ efs){
  int e = blockIdx.x*256+threadIdx.x;
  if (e>=NE) return;
  int d = dst[e];
  int pos = rowptr[d] + atomicAdd(&fill[d],1);
  eperm[pos]=e; srcs[pos]=src[e]; dsts[pos]=d;
  float2 f = reinterpret_cast<const float2*>(ef)[e];
  efs[pos] = (unsigned)f2bf(f.x) | ((unsigned)f2bf(f.y)<<16);
}

// weights -> bf16 MFMA B-fragment order: t = ((ks*4+ct)*64+l)*8+j
// value = W[ks*32+(l>>4)*8+j][ct*16+(l&15)] (0 if k>=Ksrc), W row-major [K][64]
__global__ void k_wprep(const float* __restrict__ W, ushort_t* __restrict__ frag, int Ksrc, int total){
  int t = blockIdx.x*256+threadIdx.x;
  if (t>=total) return;
  int j = t&7, l=(t>>3)&63, ct=(t>>9)&3, ks=t>>11;
  int k = ks*32 + ((l>>4)<<3) + j;
  int col = ct*16 + (l&15);
  float v = (k<Ksrc)? W[k*64+col] : 0.f;
  frag[t] = f2bf(v);
}

__global__ void k_init(const float* __restrict__ nf, const float* __restrict__ W, const float* __restrict__ b,
                       ushort_t* __restrict__ hA, ushort_t* __restrict__ emb){
  int t = blockIdx.x*256+threadIdx.x;
  if (t >= NN*64) return;
  int n=t>>6, c=t&63;
  float a = b[c];
  a += nf[n*3+0]*W[0*64+c];
  a += nf[n*3+1]*W[1*64+c];
  a += nf[n*3+2]*W[2*64+c];
  emb[t] = f2bf(a);
  hA[t] = f2bf(fmaxf(a,0.f));
}

// ------------------------- edge message kernel -------------------------
// 64 sorted edges / block, 4 waves. x = [h[dst] | h[src] | ef | pad] K=160.
// Proven round-1 structure; hidden overlays into xl slots 0-1 (per-wave region).
__launch_bounds__(256)
__global__ void k_edge(const ushort_t* __restrict__ h,
                       const int* __restrict__ srcs, const int* __restrict__ dsts,
                       const unsigned* __restrict__ efs,
                       const ushort_t* __restrict__ w1f, const ushort_t* __restrict__ w2f,
                       const float* __restrict__ b1, const float* __restrict__ b2,
                       ushort_t* __restrict__ m_s){
  __shared__ short xl[4*5*64*8];   // A-fragments, K=160; slots 0-1 reused for hidden
  int p0 = blockIdx.x*64;
  int tid = threadIdx.x;

  for (int c = tid; c < 64*20; c += 256){
    int e = c/20, cc = c - e*20;
    int p = p0 + e;
    short8 v = {0,0,0,0,0,0,0,0};
    if (cc < 8){
      v = *reinterpret_cast<const short8*>(h + (size_t)dsts[p]*64 + cc*8);
    } else if (cc < 16){
      v = *reinterpret_cast<const short8*>(h + (size_t)srcs[p]*64 + (cc-8)*8);
    } else if (cc == 16){
      unsigned u = efs[p];
      v[0] = (short)(u & 0xffffu); v[1] = (short)(u >> 16);
    }
    int w = e>>4, r = e&15, ks = cc>>2, g = cc&3;
    *reinterpret_cast<short8*>(&xl[(((w*5+ks)*64 + g*16 + r)<<3)]) = v;
  }
  __syncthreads();

  int wv = tid>>6, lane = tid&63;
  int r0 = (lane>>4)*4;
  const short8* xw = reinterpret_cast<const short8*>(xl) + wv*5*64 + lane;
  const short8* w1 = reinterpret_cast<const short8*>(w1f) + lane;
  floatx4 acc[4];
  #pragma unroll
  for (int ct=0;ct<4;ct++){ float bb=b1[ct*16+(lane&15)]; acc[ct]=(floatx4){bb,bb,bb,bb}; }
  #pragma unroll
  for (int ks=0; ks<5; ks++){
    short8 a = xw[ks*64];
    #pragma unroll
    for (int ct=0;ct<4;ct++)
      acc[ct] = __builtin_amdgcn_mfma_f32_16x16x32_bf16(a, w1[(ks*4+ct)*64], acc[ct], 0,0,0);
  }
  __syncthreads();   // full fence: all reads of slots 0-1 done before overlay
  // relu -> hidden fragments (overlay into wave's slots 0-1)
  #pragma unroll
  for (int ct=0; ct<4; ct++){
    int colk = ct*16 + (lane&15);
    int ks2 = colk>>5, g2=(colk>>3)&3, j2=colk&7;
    #pragma unroll
    for (int j=0;j<4;j++)
      xl[(((wv*5+ks2)*64 + g2*16 + (r0+j))<<3) + j2] = (short)f2bf(fmaxf(acc[ct][j],0.f));
  }
  __syncthreads();

  const short8* w2 = reinterpret_cast<const short8*>(w2f) + lane;
  floatx4 mac[4];
  #pragma unroll
  for (int ct=0;ct<4;ct++){ float bb=b2[ct*16+(lane&15)]; mac[ct]=(floatx4){bb,bb,bb,bb}; }
  #pragma unroll
  for (int ks=0; ks<2; ks++){
    short8 a = xw[ks*64];
    #pragma unroll
    for (int ct=0;ct<4;ct++)
      mac[ct] = __builtin_amdgcn_mfma_f32_16x16x32_bf16(a, w2[(ks*4+ct)*64], mac[ct], 0,0,0);
  }
  #pragma unroll
  for (int ct=0;ct<4;ct++){
    int col = ct*16+(lane&15);
    #pragma unroll
    for (int j=0;j<4;j++)
      m_s[(size_t)(p0 + wv*16 + r0 + j)*64 + col] = f2bf(mac[ct][j]);
  }
}

// ------------------------- node update kernel -------------------------
// 64 nodes / block; wave wv owns nodes wv*16..wv*16+15.
// Vectorized aggregation: lane = 4 channels x row-group, uint2 loads, shfl_xor combine.
__launch_bounds__(256)
__global__ void k_update(const ushort_t* __restrict__ m_s,
                         const int* __restrict__ rowptr,
                         const ushort_t* __restrict__ hin,
                         const ushort_t* __restrict__ w1f, const ushort_t* __restrict__ w2f,
                         const float* __restrict__ b1, const float* __restrict__ b2,
                         ushort_t* __restrict__ emb, ushort_t* __restrict__ hout){
  __shared__ short xl[4*10*64*8];  // K=320 fragments; slots 0-1 reused for hidden
  int n0 = blockIdx.x*64;
  int tid = threadIdx.x;
  int wv = tid>>6, lane = tid&63;
  int grp = lane>>4;               // row group (4 rows per load across wave)
  int cbase = (lane&15)*4;         // 4 channels per lane

  for (int q=0; q<16; q++){
    int n = n0 + wv*16 + q;
    bool nv = n < NN;
    int rp0 = nv ? rowptr[n]   : 0;
    int rp1 = nv ? rowptr[n+1] : 0;
    float sm0=0.f,sm1=0.f,sm2=0.f,sm3=0.f;
    float sq0=0.f,sq1=0.f,sq2=0.f,sq3=0.f;
    float mn0=3.4e38f,mn1=3.4e38f,mn2=3.4e38f,mn3=3.4e38f;
    float mx0=-3.4e38f,mx1=-3.4e38f,mx2=-3.4e38f,mx3=-3.4e38f;

#define ACC4(U) { \
      float v0=bf2f_lo((U).x), v1=bf2f_hi((U).x), v2=bf2f_lo((U).y), v3=bf2f_hi((U).y); \
      sm0+=v0; sq0+=v0*v0; mn0=fminf(mn0,v0); mx0=fmaxf(mx0,v0); \
      sm1+=v1; sq1+=v1*v1; mn1=fminf(mn1,v1); mx1=fmaxf(mx1,v1); \
      sm2+=v2; sq2+=v2*v2; mn2=fminf(mn2,v2); mx2=fmaxf(mx2,v2); \
      sm3+=v3; sq3+=v3*v3; mn3=fminf(mn3,v3); mx3=fmaxf(mx3,v3); }

    int p = rp0 + grp;
    for (; p + 4 < rp1; p += 8){
      uint2 ua = *reinterpret_cast<const uint2*>(m_s + (size_t)p*64 + cbase);
      uint2 ub = *reinterpret_cast<const uint2*>(m_s + (size_t)(p+4)*64 + cbase);
      ACC4(ua); ACC4(ub);
    }
    if (p < rp1){
      uint2 ua = *reinterpret_cast<const uint2*>(m_s + (size_t)p*64 + cbase);
      ACC4(ua);
    }
#undef ACC4

    // combine the 4 row-groups (lanes xor 16, 32)
#define RSUM(v) { v += __shfl_xor(v,16); v += __shfl_xor(v,32); }
#define RMIN(v) { v = fminf(v,__shfl_xor(v,16)); v = fminf(v,__shfl_xor(v,32)); }
#define RMAX(v) { v = fmaxf(v,__shfl_xor(v,16)); v = fmaxf(v,__shfl_xor(v,32)); }
    RSUM(sm0); RSUM(sm1); RSUM(sm2); RSUM(sm3);
    RSUM(sq0); RSUM(sq1); RSUM(sq2); RSUM(sq3);
    RMIN(mn0); RMIN(mn1); RMIN(mn2); RMIN(mn3);
    RMAX(mx0); RMAX(mx1); RMAX(mx2); RMAX(mx3);
#undef RSUM
#undef RMIN
#undef RMAX

    int deg = rp1 - rp0;
    float invc = 1.f / (float)(deg>0?deg:1);
    float me0=sm0*invc, me1=sm1*invc, me2=sm2*invc, me3=sm3*invc;
    float sd0=__fsqrt_rn(fmaxf(sq0*invc-me0*me0,0.f)+1e-5f);
    float sd1=__fsqrt_rn(fmaxf(sq1*invc-me1*me1,0.f)+1e-5f);
    float sd2=__fsqrt_rn(fmaxf(sq2*invc-me2*me2,0.f)+1e-5f);
    float sd3=__fsqrt_rn(fmaxf(sq3*invc-me3*me3,0.f)+1e-5f);
    if (deg<=0){ mn0=mn1=mn2=mn3=0.f; mx0=mx1=mx2=mx3=0.f; }

    // write stats into A-fragment layout: stat s -> k = s*64 + c, row q
    // grp0: std + h, grp1: min, grp2: max, grp3: mean
    auto stw = [&](int s, short4_t val){
      int k0 = s*64 + cbase;
      int ks = k0>>5, g2=(k0>>3)&3, j0 = cbase&7;
      *reinterpret_cast<short4_t*>(&xl[(((wv*10+ks)*64 + g2*16 + q)<<3) + j0]) = val;
    };
    if (grp==0){
      stw(0, (short4_t){(short)f2bf(sd0),(short)f2bf(sd1),(short)f2bf(sd2),(short)f2bf(sd3)});
      uint2 hu = {0u,0u};
      if (nv) hu = *reinterpret_cast<const uint2*>(hin + (size_t)n*64 + cbase);
      stw(4, (short4_t){(short)(hu.x&0xffffu),(short)(hu.x>>16),(short)(hu.y&0xffffu),(short)(hu.y>>16)});
    } else if (grp==1){
      stw(1, (short4_t){(short)f2bf(mn0),(short)f2bf(mn1),(short)f2bf(mn2),(short)f2bf(mn3)});
    } else if (grp==2){
      stw(2, (short4_t){(short)f2bf(mx0),(short)f2bf(mx1),(short)f2bf(mx2),(short)f2bf(mx3)});
    } else {
      stw(3, (short4_t){(short)f2bf(me0),(short)f2bf(me1),(short)f2bf(me2),(short)f2bf(me3)});
    }
  }
  __syncthreads();

  int r0 = (lane>>4)*4;
  const short8* xw = reinterpret_cast<const short8*>(xl) + wv*10*64 + lane;
  const short8* w1 = reinterpret_cast<const short8*>(w1f) + lane;
  floatx4 acc[4];
  #pragma unroll
  for (int ct=0;ct<4;ct++){ float bb=b1[ct*16+(lane&15)]; acc[ct]=(floatx4){bb,bb,bb,bb}; }
  #pragma unroll
  for (int ks=0; ks<10; ks++){
    short8 a = xw[ks*64];
    #pragma unroll
    for (int ct=0;ct<4;ct++)
      acc[ct] = __builtin_amdgcn_mfma_f32_16x16x32_bf16(a, w1[(ks*4+ct)*64], acc[ct], 0,0,0);
  }
  __syncthreads();   // full fence before overlay of slots 0-1
  #pragma unroll
  for (int ct=0; ct<4; ct++){
    int colk = ct*16 + (lane&15);
    int ks2 = colk>>5, g2=(colk>>3)&3, j2=colk&7;
    #pragma unroll
    for (int j=0;j<4;j++)
      xl[(((wv*10+ks2)*64 + g2*16 + (r0+j))<<3) + j2] = (short)f2bf(fmaxf(acc[ct][j],0.f));
  }
  __syncthreads();

  const short8* w2 = reinterpret_cast<const short8*>(w2f) + lane;
  floatx4 mac[4];
  #pragma unroll
  for (int ct=0;ct<4;ct++){ float bb=b2[ct*16+(lane&15)]; mac[ct]=(floatx4){bb,bb,bb,bb}; }
  #pragma unroll
  for (int ks=0; ks<2; ks++){
    short8 a = xw[ks*64];
    #pragma unroll
    for (int ct=0;ct<4;ct++)
      mac[ct] = __builtin_amdgcn_mfma_f32_16x16x32_bf16(a, w2[(ks*4+ct)*64], mac[ct], 0,0,0);
  }
  #pragma unroll
  for (int ct=0;ct<4;ct++){
    int col = ct*16+(lane&15);
    #pragma unroll
    for (int j=0;j<4;j++){
      int n = n0 + wv*16 + r0 + j;
      if (n < NN){
        float v = mac[ct][j];
        emb[(size_t)n*64+col] = f2bf(v);
        hout[(size_t)n*64+col] = f2bf(fmaxf(v,0.f));
      }
    }
  }
}

// ------------------------- readout kernel -------------------------
// Proven round-1 structure. x = [emb[src] | emb[dst] | ef | pad].
__launch_bounds__(256)
__global__ void k_readout(const ushort_t* __restrict__ emb,
                          const int* __restrict__ srcs, const int* __restrict__ dsts,
                          const unsigned* __restrict__ efs, const int* __restrict__ eperm,
                          const ushort_t* __restrict__ w1f,
                          const float* __restrict__ b1,
                          const float* __restrict__ w2, const float* __restrict__ b2,
                          float* __restrict__ out){
  __shared__ short xl[4*5*64*8];
  int p0 = blockIdx.x*64;
  int tid = threadIdx.x;

  for (int c = tid; c < 64*20; c += 256){
    int e = c/20, cc = c - e*20;
    int p = p0 + e;
    short8 v = {0,0,0,0,0,0,0,0};
    if (cc < 8){
      v = *reinterpret_cast<const short8*>(emb + (size_t)srcs[p]*64 + cc*8);   // attacker = src first
    } else if (cc < 16){
      v = *reinterpret_cast<const short8*>(emb + (size_t)dsts[p]*64 + (cc-8)*8);
    } else if (cc == 16){
      unsigned u = efs[p];
      v[0] = (short)(u & 0xffffu); v[1] = (short)(u >> 16);
    }
    int w = e>>4, r = e&15, ks = cc>>2, g = cc&3;
    *reinterpret_cast<short8*>(&xl[(((w*5+ks)*64 + g*16 + r)<<3)]) = v;
  }
  __syncthreads();

  int wv = tid>>6, lane = tid&63;
  int r0 = (lane>>4)*4;
  const short8* xw = reinterpret_cast<const short8*>(xl) + wv*5*64 + lane;
  const short8* w1 = reinterpret_cast<const short8*>(w1f) + lane;
  floatx4 acc[4];
  #pragma unroll
  for (int ct=0;ct<4;ct++){ float bb=b1[ct*16+(lane&15)]; acc[ct]=(floatx4){bb,bb,bb,bb}; }
  #pragma unroll
  for (int ks=0; ks<5; ks++){
    short8 a = xw[ks*64];
    #pragma unroll
    for (int ct=0;ct<4;ct++)
      acc[ct] = __builtin_amdgcn_mfma_f32_16x16x32_bf16(a, w1[(ks*4+ct)*64], acc[ct], 0,0,0);
  }
  float w2v[4];
  #pragma unroll
  for (int ct=0;ct<4;ct++) w2v[ct] = w2[ct*16+(lane&15)];
  float part[4];
  #pragma unroll
  for (int j=0;j<4;j++){
    float pj = 0.f;
    #pragma unroll
    for (int ct=0;ct<4;ct++) pj += fmaxf(acc[ct][j],0.f)*w2v[ct];
    part[j] = pj;
  }
  #pragma unroll
  for (int m=1;m<16;m<<=1){
    #pragma unroll
    for (int j=0;j<4;j++) part[j] += __shfl_xor(part[j], m, 64);
  }
  if ((lane&15)==0){
    float bb = b2[0];
    #pragma unroll
    for (int j=0;j<4;j++)
      out[eperm[p0 + wv*16 + r0 + j]] = part[j] + bb;
  }
}

// ------------------------- launcher -------------------------
extern "C" void kernel_launch(void* const* d_in, const int* in_sizes, int n_in,
                              void* d_out, int out_size, void* d_ws, size_t ws_size,
                              hipStream_t stream){
  const float* nf    = (const float*)d_in[0];
  const float* ef    = (const float*)d_in[1];
  const float* initW = (const float*)d_in[2];
  const float* initb = (const float*)d_in[3];
  const float* msgW1 = (const float*)d_in[4];
  const float* msgb1 = (const float*)d_in[5];
  const float* msgW2 = (const float*)d_in[6];
  const float* msgb2 = (const float*)d_in[7];
  const float* updW1 = (const float*)d_in[8];
  const float* updb1 = (const float*)d_in[9];
  const float* updW2 = (const float*)d_in[10];
  const float* updb2 = (const float*)d_in[11];
  const float* roW1  = (const float*)d_in[12];
  const float* rob1  = (const float*)d_in[13];
  const float* roW2  = (const float*)d_in[14];
  const float* rob2  = (const float*)d_in[15];
  const int*   eidx  = (const int*)d_in[16];
  const int* srcI = eidx;
  const int* dstI = eidx + NE;
  float* out = (float*)d_out;

  char* base = (char*)d_ws; size_t off = 0;
  auto alloc = [&](size_t b)->char*{ char* p = base + off; off = (off + b + 255) & ~(size_t)255; return p; };
  int* cnt    = (int*)alloc((size_t)NN*4);
  int* fill   = (int*)alloc((size_t)NN*4);
  int* rowptr = (int*)alloc((size_t)(NN+1)*4);
  int* bsum   = (int*)alloc(512*4);
  int* eperm  = (int*)alloc((size_t)NE*4);
  int* srcs   = (int*)alloc((size_t)NE*4);
  int* dsts   = (int*)alloc((size_t)NE*4);
  unsigned* efs = (unsigned*)alloc((size_t)NE*4);
  ushort_t* hA  = (ushort_t*)alloc((size_t)NN*64*2);
  ushort_t* hB  = (ushort_t*)alloc((size_t)NN*64*2);
  ushort_t* emb = (ushort_t*)alloc((size_t)NN*64*2);
  ushort_t* m_s = (ushort_t*)alloc((size_t)NE*64*2);
  ushort_t* msgW1f = (ushort_t*)alloc(5*2048*2);
  ushort_t* msgW2f = (ushort_t*)alloc(2*2048*2);
  ushort_t* updW1f = (ushort_t*)alloc(10*2048*2);
  ushort_t* updW2f = (ushort_t*)alloc(2*2048*2);
  ushort_t* roW1f  = (ushort_t*)alloc(5*2048*2);
  (void)ws_size; (void)in_sizes; (void)n_in; (void)out_size;

  hipMemsetAsync(cnt, 0, (size_t)NN*4, stream);
  hipMemsetAsync(fill, 0, (size_t)NN*4, stream);
  int nb = (NN+255)/256;
  k_count<<<(NE+255)/256,256,0,stream>>>(dstI,cnt);
  k_scan1<<<nb,256,0,stream>>>(cnt,bsum);
  k_scan2<<<1,512,0,stream>>>(bsum,nb);
  k_scan3<<<nb,256,0,stream>>>(cnt,bsum,rowptr);
  k_scatter<<<(NE+255)/256,256,0,stream>>>(srcI,dstI,ef,rowptr,fill,eperm,srcs,dsts,efs);
  k_wprep<<<(5*2048+255)/256,256,0,stream>>>(msgW1,msgW1f,130,5*2048);
  k_wprep<<<(2*2048+255)/256,256,0,stream>>>(msgW2,msgW2f,64,2*2048);
  k_wprep<<<(10*2048+255)/256,256,0,stream>>>(updW1,updW1f,320,10*2048);
  k_wprep<<<(2*2048+255)/256,256,0,stream>>>(updW2,updW2f,64,2*2048);
  k_wprep<<<(5*2048+255)/256,256,0,stream>>>(roW1,roW1f,130,5*2048);
  k_init<<<(NN*64+255)/256,256,0,stream>>>(nf,initW,initb,hA,emb);

  for (int it=0; it<ITERS; it++){
    const ushort_t* hin = (it&1)? hB : hA;
    ushort_t* hout      = (it&1)? hA : hB;
    k_edge<<<NE/64,256,0,stream>>>(hin,srcs,dsts,efs,msgW1f,msgW2f,msgb1,msgb2,m_s);
    k_update<<<(NN+63)/64,256,0,stream>>>(m_s,rowptr,hin,updW1f,updW2f,updb1,updb2,emb,hout);
  }
  k_readout<<<NE/64,256,0,stream>>>(emb,srcs,dsts,efs,eperm,roW1f,rob1,roW2,rob2,out);
}

// Round 5
// 1245.139 us; speedup vs baseline: 1.6962x; 1.1173x over previous
//
#include <hip/hip_runtime.h>

#define NN 100000
#define NE 1200000
#define ITERS 5

typedef __attribute__((ext_vector_type(8))) short short8;
typedef __attribute__((ext_vector_type(4))) short short4_t;
typedef __attribute__((ext_vector_type(4))) float floatx4;
typedef unsigned short ushort_t;

__device__ inline ushort_t f2bf(float f){
  unsigned u = __float_as_uint(f);
  unsigned r = (u + 0x7fffu + ((u>>16)&1u)) >> 16;
  return (ushort_t)r;
}
__device__ inline float bf2f(ushort_t u){ return __uint_as_float(((unsigned)u)<<16); }
__device__ inline float bf2f_lo(unsigned u){ return __uint_as_float(u<<16); }
__device__ inline float bf2f_hi(unsigned u){ return __uint_as_float(u & 0xffff0000u); }

// bijective XCD-chunked swizzle (m204): same-XCD hw blocks process contiguous tiles
__device__ inline int xcd_swz(int orig, int nwg){
  int q = nwg >> 3, r = nwg & 7;
  int x = orig & 7, i = orig >> 3;
  return (x < r ? x*(q+1) : r*(q+1) + (x-r)*q) + i;
}

// ------------------------- prep: counting sort by dst -------------------------
__global__ void k_count(const int* __restrict__ dst, int* __restrict__ cnt){
  int e = blockIdx.x*256 + threadIdx.x;
  if (e < NE) atomicAdd(&cnt[dst[e]], 1);
}

__global__ void k_scan1(const int* __restrict__ cnt, int* __restrict__ bsum){
  __shared__ int s[256];
  int t = threadIdx.x; int i = blockIdx.x*256 + t;
  s[t] = (i < NN) ? cnt[i] : 0; __syncthreads();
  for (int off=128; off>0; off>>=1){ if (t<off) s[t]+=s[t+off]; __syncthreads(); }
  if (t==0) bsum[blockIdx.x] = s[0];
}

__global__ void k_scan2(int* bsum, int nb){
  __shared__ int s[512];
  int t = threadIdx.x;
  int v = (t<nb)? bsum[t] : 0;
  s[t]=v; __syncthreads();
  for (int off=1; off<512; off<<=1){
    int x = (t>=off)? s[t-off] : 0; __syncthreads();
    s[t]+=x; __syncthreads();
  }
  if (t<nb) bsum[t] = s[t]-v; // exclusive
}

__global__ void k_scan3(const int* __restrict__ cnt, const int* __restrict__ bsum, int* __restrict__ rowptr){
  __shared__ int s[256];
  int t=threadIdx.x; int i = blockIdx.x*256+t;
  int v = (i<NN)? cnt[i]:0;
  s[t]=v; __syncthreads();
  for (int off=1; off<256; off<<=1){
    int x = (t>=off)? s[t-off] : 0; __syncthreads();
    s[t] += x; __syncthreads();
  }
  if (i<NN) rowptr[i] = bsum[blockIdx.x] + s[t] - v;
  if (i==0) rowptr[NN] = NE;
}

__global__ void k_scatter(const int* __restrict__ src, const int* __restrict__ dst,
                          const float* __restrict__ ef,
                          const int* __restrict__ rowptr, int* __restrict__ fill,
                          int* __restrict__ eperm, int* __restrict__ srcs, int* __restrict__ dsts,
                          unsigned* __restrict__ efs){
  int e = blockIdx.x*256+threadIdx.x;
  if (e>=NE) return;
  int d = dst[e];
  int pos = rowptr[d] + atomicAdd(&fill[d],1);
  eperm[pos]=e; srcs[pos]=src[e]; dsts[pos]=d;
  float2 f = reinterpret_cast<const float2*>(ef)[e];
  efs[pos] = (unsigned)f2bf(f.x) | ((unsigned)f2bf(f.y)<<16);
}

// weights -> bf16 MFMA B-fragment order: t = ((ks*4+ct)*64+l)*8+j
// value = W[ks*32+(l>>4)*8+j][ct*16+(l&15)] (0 if k>=Ksrc), W row-major [K][64]
__global__ void k_wprep(const float* __restrict__ W, ushort_t* __restrict__ frag, int Ksrc, int total){
  int t = blockIdx.x*256+threadIdx.x;
  if (t>=total) return;
  int j = t&7, l=(t>>3)&63, ct=(t>>9)&3, ks=t>>11;
  int k = ks*32 + ((l>>4)<<3) + j;
  int col = ct*16 + (l&15);
  float v = (k<Ksrc)? W[k*64+col] : 0.f;
  frag[t] = f2bf(v);
}

__global__ void k_init(const float* __restrict__ nf, const float* __restrict__ W, const float* __restrict__ b,
                       ushort_t* __restrict__ hA, ushort_t* __restrict__ emb){
  int t = blockIdx.x*256+threadIdx.x;
  if (t >= NN*64) return;
  int n=t>>6, c=t&63;
  float a = b[c];
  a += nf[n*3+0]*W[0*64+c];
  a += nf[n*3+1]*W[1*64+c];
  a += nf[n*3+2]*W[2*64+c];
  emb[t] = f2bf(a);
  hA[t] = f2bf(fmaxf(a,0.f));
}

// ------------------------- edge message kernel -------------------------
// 64 sorted edges / block, 4 waves. x = [h[dst] | h[src] | ef | pad] K=160.
// Transposed gather: thread (wv,lane) iter ks handles edge wv*16+(lane&15),
// chunk ks*4+(lane>>4) -> LDS write addr = ((wv*5+ks)*64+lane)*16B, conflict-free.
__launch_bounds__(256)
__global__ void k_edge(const ushort_t* __restrict__ h,
                       const int* __restrict__ srcs, const int* __restrict__ dsts,
                       const unsigned* __restrict__ efs,
                       const ushort_t* __restrict__ w1f, const ushort_t* __restrict__ w2f,
                       const float* __restrict__ b1, const float* __restrict__ b2,
                       ushort_t* __restrict__ m_s){
  __shared__ short xl[4*5*64*8];   // A-fragments, K=160; slots 0-1 reused for hidden
  int p0 = xcd_swz(blockIdx.x, NE/64) * 64;
  int tid = threadIdx.x;
  int wv = tid>>6, lane = tid&63;
  int r = lane&15, g = lane>>4;

  int p = p0 + wv*16 + r;
  int dv = dsts[p];
  int sv = srcs[p];
  unsigned ev = efs[p];

  #pragma unroll
  for (int ks=0; ks<5; ks++){
    int cc = ks*4 + g;
    short8 v = {0,0,0,0,0,0,0,0};
    if (cc < 16){
      int row = (cc<8)? dv : sv;
      v = *reinterpret_cast<const short8*>(h + (size_t)row*64 + (cc&7)*8);
    } else if (cc == 16){
      v[0] = (short)(ev & 0xffffu); v[1] = (short)(ev >> 16);
    }
    *reinterpret_cast<short8*>(&xl[(((wv*5+ks)*64 + lane)<<3)]) = v;
  }
  __syncthreads();

  int r0 = (lane>>4)*4;
  const short8* xw = reinterpret_cast<const short8*>(xl) + wv*5*64 + lane;
  const short8* w1 = reinterpret_cast<const short8*>(w1f) + lane;
  floatx4 acc[4];
  #pragma unroll
  for (int ct=0;ct<4;ct++){ float bb=b1[ct*16+(lane&15)]; acc[ct]=(floatx4){bb,bb,bb,bb}; }
  #pragma unroll
  for (int ks=0; ks<5; ks++){
    short8 a = xw[ks*64];
    #pragma unroll
    for (int ct=0;ct<4;ct++)
      acc[ct] = __builtin_amdgcn_mfma_f32_16x16x32_bf16(a, w1[(ks*4+ct)*64], acc[ct], 0,0,0);
  }
  __syncthreads();   // full fence: all reads of slots 0-1 done before overlay
  // relu -> hidden fragments (overlay into wave's slots 0-1)
  #pragma unroll
  for (int ct=0; ct<4; ct++){
    int colk = ct*16 + (lane&15);
    int ks2 = colk>>5, g2=(colk>>3)&3, j2=colk&7;
    #pragma unroll
    for (int j=0;j<4;j++)
      xl[(((wv*5+ks2)*64 + g2*16 + (r0+j))<<3) + j2] = (short)f2bf(fmaxf(acc[ct][j],0.f));
  }
  __syncthreads();

  const short8* w2 = reinterpret_cast<const short8*>(w2f) + lane;
  floatx4 mac[4];
  #pragma unroll
  for (int ct=0;ct<4;ct++){ float bb=b2[ct*16+(lane&15)]; mac[ct]=(floatx4){bb,bb,bb,bb}; }
  #pragma unroll
  for (int ks=0; ks<2; ks++){
    short8 a = xw[ks*64];
    #pragma unroll
    for (int ct=0;ct<4;ct++)
      mac[ct] = __builtin_amdgcn_mfma_f32_16x16x32_bf16(a, w2[(ks*4+ct)*64], mac[ct], 0,0,0);
  }
  #pragma unroll
  for (int ct=0;ct<4;ct++){
    int col = ct*16+(lane&15);
    #pragma unroll
    for (int j=0;j<4;j++)
      m_s[(size_t)(p0 + wv*16 + r0 + j)*64 + col] = f2bf(mac[ct][j]);
  }
}

// ------------------------- node update kernel -------------------------
// 64 nodes / block; wave wv owns nodes wv*16..wv*16+15.
// Vectorized aggregation: lane = 4 channels x row-group, uint2 loads, shfl_xor combine.
__launch_bounds__(256)
__global__ void k_update(const ushort_t* __restrict__ m_s,
                         const int* __restrict__ rowptr,
                         const ushort_t* __restrict__ hin,
                         const ushort_t* __restrict__ w1f, const ushort_t* __restrict__ w2f,
                         const float* __restrict__ b1, const float* __restrict__ b2,
                         ushort_t* __restrict__ emb, ushort_t* __restrict__ hout){
  __shared__ short xl[4*10*64*8];  // K=320 fragments; slots 0-1 reused for hidden
  int n0 = blockIdx.x*64;
  int tid = threadIdx.x;
  int wv = tid>>6, lane = tid&63;
  int grp = lane>>4;               // row group (4 rows per load across wave)
  int cbase = (lane&15)*4;         // 4 channels per lane

  for (int q=0; q<16; q++){
    int n = n0 + wv*16 + q;
    bool nv = n < NN;
    int rp0 = nv ? rowptr[n]   : 0;
    int rp1 = nv ? rowptr[n+1] : 0;
    float sm0=0.f,sm1=0.f,sm2=0.f,sm3=0.f;
    float sq0=0.f,sq1=0.f,sq2=0.f,sq3=0.f;
    float mn0=3.4e38f,mn1=3.4e38f,mn2=3.4e38f,mn3=3.4e38f;
    float mx0=-3.4e38f,mx1=-3.4e38f,mx2=-3.4e38f,mx3=-3.4e38f;

#define ACC4(U) { \
      float v0=bf2f_lo((U).x), v1=bf2f_hi((U).x), v2=bf2f_lo((U).y), v3=bf2f_hi((U).y); \
      sm0+=v0; sq0+=v0*v0; mn0=fminf(mn0,v0); mx0=fmaxf(mx0,v0); \
      sm1+=v1; sq1+=v1*v1; mn1=fminf(mn1,v1); mx1=fmaxf(mx1,v1); \
      sm2+=v2; sq2+=v2*v2; mn2=fminf(mn2,v2); mx2=fmaxf(mx2,v2); \
      sm3+=v3; sq3+=v3*v3; mn3=fminf(mn3,v3); mx3=fmaxf(mx3,v3); }

    int p = rp0 + grp;
    for (; p + 4 < rp1; p += 8){
      uint2 ua = *reinterpret_cast<const uint2*>(m_s + (size_t)p*64 + cbase);
      uint2 ub = *reinterpret_cast<const uint2*>(m_s + (size_t)(p+4)*64 + cbase);
      ACC4(ua); ACC4(ub);
    }
    if (p < rp1){
      uint2 ua = *reinterpret_cast<const uint2*>(m_s + (size_t)p*64 + cbase);
      ACC4(ua);
    }
#undef ACC4

    // combine the 4 row-groups (lanes xor 16, 32)
#define RSUM(v) { v += __shfl_xor(v,16); v += __shfl_xor(v,32); }
#define RMIN(v) { v = fminf(v,__shfl_xor(v,16)); v = fminf(v,__shfl_xor(v,32)); }
#define RMAX(v) { v = fmaxf(v,__shfl_xor(v,16)); v = fmaxf(v,__shfl_xor(v,32)); }
    RSUM(sm0); RSUM(sm1); RSUM(sm2); RSUM(sm3);
    RSUM(sq0); RSUM(sq1); RSUM(sq2); RSUM(sq3);
    RMIN(mn0); RMIN(mn1); RMIN(mn2); RMIN(mn3);
    RMAX(mx0); RMAX(mx1); RMAX(mx2); RMAX(mx3);
#undef RSUM
#undef RMIN
#undef RMAX

    int deg = rp1 - rp0;
    float invc = 1.f / (float)(deg>0?deg:1);
    float me0=sm0*invc, me1=sm1*invc, me2=sm2*invc, me3=sm3*invc;
    float sd0=__fsqrt_rn(fmaxf(sq0*invc-me0*me0,0.f)+1e-5f);
    float sd1=__fsqrt_rn(fmaxf(sq1*invc-me1*me1,0.f)+1e-5f);
    float sd2=__fsqrt_rn(fmaxf(sq2*invc-me2*me2,0.f)+1e-5f);
    float sd3=__fsqrt_rn(fmaxf(sq3*invc-me3*me3,0.f)+1e-5f);
    if (deg<=0){ mn0=mn1=mn2=mn3=0.f; mx0=mx1=mx2=mx3=0.f; }

    // write stats into A-fragment layout: stat s -> k = s*64 + c, row q
    // grp0: std + h, grp1: min, grp2: max, grp3: mean
    auto stw = [&](int s, short4_t val){
      int k0 = s*64 + cbase;
      int ks = k0>>5, g2=(k0>>3)&3, j0 = cbase&7;
      *reinterpret_cast<short4_t*>(&xl[(((wv*10+ks)*64 + g2*16 + q)<<3) + j0]) = val;
    };
    if (grp==0){
      stw(0, (short4_t){(short)f2bf(sd0),(short)f2bf(sd1),(short)f2bf(sd2),(short)f2bf(sd3)});
      uint2 hu = {0u,0u};
      if (nv) hu = *reinterpret_cast<const uint2*>(hin + (size_t)n*64 + cbase);
      stw(4, (short4_t){(short)(hu.x&0xffffu),(short)(hu.x>>16),(short)(hu.y&0xffffu),(short)(hu.y>>16)});
    } else if (grp==1){
      stw(1, (short4_t){(short)f2bf(mn0),(short)f2bf(mn1),(short)f2bf(mn2),(short)f2bf(mn3)});
    } else if (grp==2){
      stw(2, (short4_t){(short)f2bf(mx0),(short)f2bf(mx1),(short)f2bf(mx2),(short)f2bf(mx3)});
    } else {
      stw(3, (short4_t){(short)f2bf(me0),(short)f2bf(me1),(short)f2bf(me2),(short)f2bf(me3)});
    }
  }
  __syncthreads();

  int r0 = (lane>>4)*4;
  const short8* xw = reinterpret_cast<const short8*>(xl) + wv*10*64 + lane;
  const short8* w1 = reinterpret_cast<const short8*>(w1f) + lane;
  floatx4 acc[4];
  #pragma unroll
  for (int ct=0;ct<4;ct++){ float bb=b1[ct*16+(lane&15)]; acc[ct]=(floatx4){bb,bb,bb,bb}; }
  #pragma unroll
  for (int ks=0; ks<10; ks++){
    short8 a = xw[ks*64];
    #pragma unroll
    for (int ct=0;ct<4;ct++)
      acc[ct] = __builtin_amdgcn_mfma_f32_16x16x32_bf16(a, w1[(ks*4+ct)*64], acc[ct], 0,0,0);
  }
  __syncthreads();   // full fence before overlay of slots 0-1
  #pragma unroll
  for (int ct=0; ct<4; ct++){
    int colk = ct*16 + (lane&15);
    int ks2 = colk>>5, g2=(colk>>3)&3, j2=colk&7;
    #pragma unroll
    for (int j=0;j<4;j++)
      xl[(((wv*10+ks2)*64 + g2*16 + (r0+j))<<3) + j2] = (short)f2bf(fmaxf(acc[ct][j],0.f));
  }
  __syncthreads();

  const short8* w2 = reinterpret_cast<const short8*>(w2f) + lane;
  floatx4 mac[4];
  #pragma unroll
  for (int ct=0;ct<4;ct++){ float bb=b2[ct*16+(lane&15)]; mac[ct]=(floatx4){bb,bb,bb,bb}; }
  #pragma unroll
  for (int ks=0; ks<2; ks++){
    short8 a = xw[ks*64];
    #pragma unroll
    for (int ct=0;ct<4;ct++)
      mac[ct] = __builtin_amdgcn_mfma_f32_16x16x32_bf16(a, w2[(ks*4+ct)*64], mac[ct], 0,0,0);
  }
  #pragma unroll
  for (int ct=0;ct<4;ct++){
    int col = ct*16+(lane&15);
    #pragma unroll
    for (int j=0;j<4;j++){
      int n = n0 + wv*16 + r0 + j;
      if (n < NN){
        float v = mac[ct][j];
        emb[(size_t)n*64+col] = f2bf(v);
        hout[(size_t)n*64+col] = f2bf(fmaxf(v,0.f));
      }
    }
  }
}

// ------------------------- readout kernel -------------------------
// x = [emb[src] | emb[dst] | ef | pad]; transposed conflict-free gather.
__launch_bounds__(256)
__global__ void k_readout(const ushort_t* __restrict__ emb,
                          const int* __restrict__ srcs, const int* __restrict__ dsts,
                          const unsigned* __restrict__ efs, const int* __restrict__ eperm,
                          const ushort_t* __restrict__ w1f,
                          const float* __restrict__ b1,
                          const float* __restrict__ w2, const float* __restrict__ b2,
                          float* __restrict__ out){
  __shared__ short xl[4*5*64*8];
  int p0 = xcd_swz(blockIdx.x, NE/64) * 64;
  int tid = threadIdx.x;
  int wv = tid>>6, lane = tid&63;
  int r = lane&15, g = lane>>4;

  int p = p0 + wv*16 + r;
  int dv = dsts[p];
  int sv = srcs[p];
  unsigned ev = efs[p];

  #pragma unroll
  for (int ks=0; ks<5; ks++){
    int cc = ks*4 + g;
    short8 v = {0,0,0,0,0,0,0,0};
    if (cc < 16){
      int row = (cc<8)? sv : dv;   // attacker = src first
      v = *reinterpret_cast<const short8*>(emb + (size_t)row*64 + (cc&7)*8);
    } else if (cc == 16){
      v[0] = (short)(ev & 0xffffu); v[1] = (short)(ev >> 16);
    }
    *reinterpret_cast<short8*>(&xl[(((wv*5+ks)*64 + lane)<<3)]) = v;
  }
  __syncthreads();

  int r0 = (lane>>4)*4;
  const short8* xw = reinterpret_cast<const short8*>(xl) + wv*5*64 + lane;
  const short8* w1 = reinterpret_cast<const short8*>(w1f) + lane;
  floatx4 acc[4];
  #pragma unroll
  for (int ct=0;ct<4;ct++){ float bb=b1[ct*16+(lane&15)]; acc[ct]=(floatx4){bb,bb,bb,bb}; }
  #pragma unroll
  for (int ks=0; ks<5; ks++){
    short8 a = xw[ks*64];
    #pragma unroll
    for (int ct=0;ct<4;ct++)
      acc[ct] = __builtin_amdgcn_mfma_f32_16x16x32_bf16(a, w1[(ks*4+ct)*64], acc[ct], 0,0,0);
  }
  float w2v[4];
  #pragma unroll
  for (int ct=0;ct<4;ct++) w2v[ct] = w2[ct*16+(lane&15)];
  float part[4];
  #pragma unroll
  for (int j=0;j<4;j++){
    float pj = 0.f;
    #pragma unroll
    for (int ct=0;ct<4;ct++) pj += fmaxf(acc[ct][j],0.f)*w2v[ct];
    part[j] = pj;
  }
  #pragma unroll
  for (int m=1;m<16;m<<=1){
    #pragma unroll
    for (int j=0;j<4;j++) part[j] += __shfl_xor(part[j], m, 64);
  }
  if ((lane&15)==0){
    float bb = b2[0];
    #pragma unroll
    for (int j=0;j<4;j++)
      out[eperm[p0 + wv*16 + r0 + j]] = part[j] + bb;
  }
}

// ------------------------- launcher -------------------------
extern "C" void kernel_launch(void* const* d_in, const int* in_sizes, int n_in,
                              void* d_out, int out_size, void* d_ws, size_t ws_size,
                              hipStream_t stream){
  const float* nf    = (const float*)d_in[0];
  const float* ef    = (const float*)d_in[1];
  const float* initW = (const float*)d_in[2];
  const float* initb = (const float*)d_in[3];
  const float* msgW1 = (const float*)d_in[4];
  const float* msgb1 = (const float*)d_in[5];
  const float* msgW2 = (const float*)d_in[6];
  const float* msgb2 = (const float*)d_in[7];
  const float* updW1 = (const float*)d_in[8];
  const float* updb1 = (const float*)d_in[9];
  const float* updW2 = (const float*)d_in[10];
  const float* updb2 = (const float*)d_in[11];
  const float* roW1  = (const float*)d_in[12];
  const float* rob1  = (const float*)d_in[13];
  const float* roW2  = (const float*)d_in[14];
  const float* rob2  = (const float*)d_in[15];
  const int*   eidx  = (const int*)d_in[16];
  const int* srcI = eidx;
  const int* dstI = eidx + NE;
  float* out = (float*)d_out;

  char* base = (char*)d_ws; size_t off = 0;
  auto alloc = [&](size_t b)->char*{ char* p = base + off; off = (off + b + 255) & ~(size_t)255; return p; };
  int* cnt    = (int*)alloc((size_t)NN*4);
  int* fill   = (int*)alloc((size_t)NN*4);
  int* rowptr = (int*)alloc((size_t)(NN+1)*4);
  int* bsum   = (int*)alloc(512*4);
  int* eperm  = (int*)alloc((size_t)NE*4);
  int* srcs   = (int*)alloc((size_t)NE*4);
  int* dsts   = (int*)alloc((size_t)NE*4);
  unsigned* efs = (unsigned*)alloc((size_t)NE*4);
  ushort_t* hA  = (ushort_t*)alloc((size_t)NN*64*2);
  ushort_t* hB  = (ushort_t*)alloc((size_t)NN*64*2);
  ushort_t* emb = (ushort_t*)alloc((size_t)NN*64*2);
  ushort_t* m_s = (ushort_t*)alloc((size_t)NE*64*2);
  ushort_t* msgW1f = (ushort_t*)alloc(5*2048*2);
  ushort_t* msgW2f = (ushort_t*)alloc(2*2048*2);
  ushort_t* updW1f = (ushort_t*)alloc(10*2048*2);
  ushort_t* updW2f = (ushort_t*)alloc(2*2048*2);
  ushort_t* roW1f  = (ushort_t*)alloc(5*2048*2);
  (void)ws_size; (void)in_sizes; (void)n_in; (void)out_size;

  hipMemsetAsync(cnt, 0, (size_t)NN*4, stream);
  hipMemsetAsync(fill, 0, (size_t)NN*4, stream);
  int nb = (NN+255)/256;
  k_count<<<(NE+255)/256,256,0,stream>>>(dstI,cnt);
  k_scan1<<<nb,256,0,stream>>>(cnt,bsum);
  k_scan2<<<1,512,0,stream>>>(bsum,nb);
  k_scan3<<<nb,256,0,stream>>>(cnt,bsum,rowptr);
  k_scatter<<<(NE+255)/256,256,0,stream>>>(srcI,dstI,ef,rowptr,fill,eperm,srcs,dsts,efs);
  k_wprep<<<(5*2048+255)/256,256,0,stream>>>(msgW1,msgW1f,130,5*2048);
  k_wprep<<<(2*2048+255)/256,256,0,stream>>>(msgW2,msgW2f,64,2*2048);
  k_wprep<<<(10*2048+255)/256,256,0,stream>>>(updW1,updW1f,320,10*2048);
  k_wprep<<<(2*2048+255)/256,256,0,stream>>>(updW2,updW2f,64,2*2048);
  k_wprep<<<(5*2048+255)/256,256,0,stream>>>(roW1,roW1f,130,5*2048);
  k_init<<<(NN*64+255)/256,256,0,stream>>>(nf,initW,initb,hA,emb);

  for (int it=0; it<ITERS; it++){
    const ushort_t* hin = (it&1)? hB : hA;
    ushort_t* hout      = (it&1)? hA : hB;
    k_edge<<<NE/64,256,0,stream>>>(hin,srcs,dsts,efs,msgW1f,msgW2f,msgb1,msgb2,m_s);
    k_update<<<(NN+63)/64,256,0,stream>>>(m_s,rowptr,hin,updW1f,updW2f,updb1,updb2,emb,hout);
  }
  k_readout<<<NE/64,256,0,stream>>>(emb,srcs,dsts,efs,eperm,roW1f,rob1,roW2,rob2,out);
}

// Round 6
// 1240.565 us; speedup vs baseline: 1.7025x; 1.0037x over previous
//
#include <hip/hip_runtime.h>

#define NN 100000
#define NE 1200000
#define ITERS 5

typedef __attribute__((ext_vector_type(8))) short short8;
typedef __attribute__((ext_vector_type(4))) short short4_t;
typedef __attribute__((ext_vector_type(4))) float floatx4;
typedef unsigned short ushort_t;

__device__ inline ushort_t f2bf(float f){
  unsigned u = __float_as_uint(f);
  unsigned r = (u + 0x7fffu + ((u>>16)&1u)) >> 16;
  return (ushort_t)r;
}
__device__ inline float bf2f(ushort_t u){ return __uint_as_float(((unsigned)u)<<16); }
__device__ inline float bf2f_lo(unsigned u){ return __uint_as_float(u<<16); }
__device__ inline float bf2f_hi(unsigned u){ return __uint_as_float(u & 0xffff0000u); }

// bijective XCD-chunked swizzle (m204): same-XCD hw blocks process contiguous tiles
__device__ inline int xcd_swz(int orig, int nwg){
  int q = nwg >> 3, r = nwg & 7;
  int x = orig & 7, i = orig >> 3;
  return (x < r ? x*(q+1) : r*(q+1) + (x-r)*q) + i;
}

// ------------------------- prep: counting sort by dst -------------------------
__global__ void k_count(const int* __restrict__ dst, int* __restrict__ cnt){
  int e = blockIdx.x*256 + threadIdx.x;
  if (e < NE) atomicAdd(&cnt[dst[e]], 1);
}

__global__ void k_scan1(const int* __restrict__ cnt, int* __restrict__ bsum){
  __shared__ int s[256];
  int t = threadIdx.x; int i = blockIdx.x*256 + t;
  s[t] = (i < NN) ? cnt[i] : 0; __syncthreads();
  for (int off=128; off>0; off>>=1){ if (t<off) s[t]+=s[t+off]; __syncthreads(); }
  if (t==0) bsum[blockIdx.x] = s[0];
}

__global__ void k_scan2(int* bsum, int nb){
  __shared__ int s[512];
  int t = threadIdx.x;
  int v = (t<nb)? bsum[t] : 0;
  s[t]=v; __syncthreads();
  for (int off=1; off<512; off<<=1){
    int x = (t>=off)? s[t-off] : 0; __syncthreads();
    s[t]+=x; __syncthreads();
  }
  if (t<nb) bsum[t] = s[t]-v; // exclusive
}

__global__ void k_scan3(const int* __restrict__ cnt, const int* __restrict__ bsum, int* __restrict__ rowptr){
  __shared__ int s[256];
  int t=threadIdx.x; int i = blockIdx.x*256+t;
  int v = (i<NN)? cnt[i]:0;
  s[t]=v; __syncthreads();
  for (int off=1; off<256; off<<=1){
    int x = (t>=off)? s[t-off] : 0; __syncthreads();
    s[t] += x; __syncthreads();
  }
  if (i<NN) rowptr[i] = bsum[blockIdx.x] + s[t] - v;
  if (i==0) rowptr[NN] = NE;
}

// one 16B record per sorted edge: {src, dst, ef_bf16x2, 0}
__global__ void k_scatter(const int* __restrict__ src, const int* __restrict__ dst,
                          const float* __restrict__ ef,
                          const int* __restrict__ rowptr, int* __restrict__ fill,
                          int4* __restrict__ edges){
  int e = blockIdx.x*256+threadIdx.x;
  if (e>=NE) return;
  int d = dst[e];
  int pos = rowptr[d] + atomicAdd(&fill[d],1);
  float2 f = reinterpret_cast<const float2*>(ef)[e];
  int efp = (int)((unsigned)f2bf(f.x) | ((unsigned)f2bf(f.y)<<16));
  edges[pos] = make_int4(src[e], d, efp, 0);
}

// weights -> bf16 MFMA B-fragment order: t = ((ks*4+ct)*64+l)*8+j
// value = W[ks*32+(l>>4)*8+j][ct*16+(l&15)] (0 if k>=Ksrc), W row-major [K][64]
__global__ void k_wprep(const float* __restrict__ W, ushort_t* __restrict__ frag, int Ksrc, int total){
  int t = blockIdx.x*256+threadIdx.x;
  if (t>=total) return;
  int j = t&7, l=(t>>3)&63, ct=(t>>9)&3, ks=t>>11;
  int k = ks*32 + ((l>>4)<<3) + j;
  int col = ct*16 + (l&15);
  float v = (k<Ksrc)? W[k*64+col] : 0.f;
  frag[t] = f2bf(v);
}

__global__ void k_init(const float* __restrict__ nf, const float* __restrict__ W, const float* __restrict__ b,
                       ushort_t* __restrict__ hA, ushort_t* __restrict__ emb){
  int t = blockIdx.x*256+threadIdx.x;
  if (t >= NN*64) return;
  int n=t>>6, c=t&63;
  float a = b[c];
  a += nf[n*3+0]*W[0*64+c];
  a += nf[n*3+1]*W[1*64+c];
  a += nf[n*3+2]*W[2*64+c];
  emb[t] = f2bf(a);
  hA[t] = f2bf(fmaxf(a,0.f));
}

// ------------------------- edge message kernel -------------------------
// 64 sorted edges / block, 4 waves. Layer-1 A-fragments come STRAIGHT from the
// gather registers (lane (r,g) slot ks holds chunk cc=ks*4+g of edge wv*16+r,
// which is exactly A row=lane&15, k=ks*32+(lane>>4)*8+j). LDS only for the
// hidden-layer transpose (2 slots/wave = 8KB).
__launch_bounds__(256)
__global__ void k_edge(const ushort_t* __restrict__ h,
                       const int4* __restrict__ edges,
                       const ushort_t* __restrict__ w1f, const ushort_t* __restrict__ w2f,
                       const float* __restrict__ b1, const float* __restrict__ b2,
                       ushort_t* __restrict__ m_s){
  __shared__ short hl[4*2*64*8];   // hidden A-fragments, K=64
  int p0 = xcd_swz(blockIdx.x, NE/64) * 64;
  int tid = threadIdx.x;
  int wv = tid>>6, lane = tid&63;
  int r = lane&15, g = lane>>4;

  int p = p0 + wv*16 + r;
  int4 rec = edges[p];
  int sv = rec.x, dv = rec.y;
  unsigned ev = (unsigned)rec.z;

  short8 v[5];
  #pragma unroll
  for (int ks=0; ks<5; ks++){
    int cc = ks*4 + g;
    short8 x = {0,0,0,0,0,0,0,0};
    if (cc < 16){
      int row = (cc<8)? dv : sv;
      x = *reinterpret_cast<const short8*>(h + (size_t)row*64 + (cc&7)*8);
    } else if (cc == 16){
      x[0] = (short)(ev & 0xffffu); x[1] = (short)(ev >> 16);
    }
    v[ks] = x;
  }

  const short8* w1 = reinterpret_cast<const short8*>(w1f) + lane;
  floatx4 acc[4];
  #pragma unroll
  for (int ct=0;ct<4;ct++){ float bb=b1[ct*16+(lane&15)]; acc[ct]=(floatx4){bb,bb,bb,bb}; }
  #pragma unroll
  for (int ks=0; ks<5; ks++){
    #pragma unroll
    for (int ct=0;ct<4;ct++)
      acc[ct] = __builtin_amdgcn_mfma_f32_16x16x32_bf16(v[ks], w1[(ks*4+ct)*64], acc[ct], 0,0,0);
  }

  // relu -> hidden A-fragments via wave-local LDS transpose
  int r0 = (lane>>4)*4;
  #pragma unroll
  for (int ct=0; ct<4; ct++){
    int colk = ct*16 + (lane&15);
    int ks2 = colk>>5, g2=(colk>>3)&3, j2=colk&7;
    #pragma unroll
    for (int j=0;j<4;j++)
      hl[(((wv*2+ks2)*64 + g2*16 + (r0+j))<<3) + j2] = (short)f2bf(fmaxf(acc[ct][j],0.f));
  }
  __syncthreads();

  const short8* hw = reinterpret_cast<const short8*>(hl) + wv*2*64 + lane;
  const short8* w2 = reinterpret_cast<const short8*>(w2f) + lane;
  floatx4 mac[4];
  #pragma unroll
  for (int ct=0;ct<4;ct++){ float bb=b2[ct*16+(lane&15)]; mac[ct]=(floatx4){bb,bb,bb,bb}; }
  #pragma unroll
  for (int ks=0; ks<2; ks++){
    short8 a = hw[ks*64];
    #pragma unroll
    for (int ct=0;ct<4;ct++)
      mac[ct] = __builtin_amdgcn_mfma_f32_16x16x32_bf16(a, w2[(ks*4+ct)*64], mac[ct], 0,0,0);
  }
  #pragma unroll
  for (int ct=0;ct<4;ct++){
    int col = ct*16+(lane&15);
    #pragma unroll
    for (int j=0;j<4;j++)
      m_s[(size_t)(p0 + wv*16 + r0 + j)*64 + col] = f2bf(mac[ct][j]);
  }
}

// ------------------------- node update kernel -------------------------
// 64 nodes / block; wave wv owns nodes wv*16..wv*16+15. (proven structure)
__launch_bounds__(256)
__global__ void k_update(const ushort_t* __restrict__ m_s,
                         const int* __restrict__ rowptr,
                         const ushort_t* __restrict__ hin,
                         const ushort_t* __restrict__ w1f, const ushort_t* __restrict__ w2f,
                         const float* __restrict__ b1, const float* __restrict__ b2,
                         ushort_t* __restrict__ emb, ushort_t* __restrict__ hout){
  __shared__ short xl[4*10*64*8];  // K=320 fragments; slots 0-1 reused for hidden
  int n0 = blockIdx.x*64;
  int tid = threadIdx.x;
  int wv = tid>>6, lane = tid&63;
  int grp = lane>>4;               // row group (4 rows per load across wave)
  int cbase = (lane&15)*4;         // 4 channels per lane

  for (int q=0; q<16; q++){
    int n = n0 + wv*16 + q;
    bool nv = n < NN;
    int rp0 = nv ? rowptr[n]   : 0;
    int rp1 = nv ? rowptr[n+1] : 0;
    float sm0=0.f,sm1=0.f,sm2=0.f,sm3=0.f;
    float sq0=0.f,sq1=0.f,sq2=0.f,sq3=0.f;
    float mn0=3.4e38f,mn1=3.4e38f,mn2=3.4e38f,mn3=3.4e38f;
    float mx0=-3.4e38f,mx1=-3.4e38f,mx2=-3.4e38f,mx3=-3.4e38f;

#define ACC4(U) { \
      float v0=bf2f_lo((U).x), v1=bf2f_hi((U).x), v2=bf2f_lo((U).y), v3=bf2f_hi((U).y); \
      sm0+=v0; sq0+=v0*v0; mn0=fminf(mn0,v0); mx0=fmaxf(mx0,v0); \
      sm1+=v1; sq1+=v1*v1; mn1=fminf(mn1,v1); mx1=fmaxf(mx1,v1); \
      sm2+=v2; sq2+=v2*v2; mn2=fminf(mn2,v2); mx2=fmaxf(mx2,v2); \
      sm3+=v3; sq3+=v3*v3; mn3=fminf(mn3,v3); mx3=fmaxf(mx3,v3); }

    int p = rp0 + grp;
    for (; p + 4 < rp1; p += 8){
      uint2 ua = *reinterpret_cast<const uint2*>(m_s + (size_t)p*64 + cbase);
      uint2 ub = *reinterpret_cast<const uint2*>(m_s + (size_t)(p+4)*64 + cbase);
      ACC4(ua); ACC4(ub);
    }
    if (p < rp1){
      uint2 ua = *reinterpret_cast<const uint2*>(m_s + (size_t)p*64 + cbase);
      ACC4(ua);
    }
#undef ACC4

    // combine the 4 row-groups (lanes xor 16, 32)
#define RSUM(v) { v += __shfl_xor(v,16); v += __shfl_xor(v,32); }
#define RMIN(v) { v = fminf(v,__shfl_xor(v,16)); v = fminf(v,__shfl_xor(v,32)); }
#define RMAX(v) { v = fmaxf(v,__shfl_xor(v,16)); v = fmaxf(v,__shfl_xor(v,32)); }
    RSUM(sm0); RSUM(sm1); RSUM(sm2); RSUM(sm3);
    RSUM(sq0); RSUM(sq1); RSUM(sq2); RSUM(sq3);
    RMIN(mn0); RMIN(mn1); RMIN(mn2); RMIN(mn3);
    RMAX(mx0); RMAX(mx1); RMAX(mx2); RMAX(mx3);
#undef RSUM
#undef RMIN
#undef RMAX

    int deg = rp1 - rp0;
    float invc = 1.f / (float)(deg>0?deg:1);
    float me0=sm0*invc, me1=sm1*invc, me2=sm2*invc, me3=sm3*invc;
    float sd0=__fsqrt_rn(fmaxf(sq0*invc-me0*me0,0.f)+1e-5f);
    float sd1=__fsqrt_rn(fmaxf(sq1*invc-me1*me1,0.f)+1e-5f);
    float sd2=__fsqrt_rn(fmaxf(sq2*invc-me2*me2,0.f)+1e-5f);
    float sd3=__fsqrt_rn(fmaxf(sq3*invc-me3*me3,0.f)+1e-5f);
    if (deg<=0){ mn0=mn1=mn2=mn3=0.f; mx0=mx1=mx2=mx3=0.f; }

    // write stats into A-fragment layout: stat s -> k = s*64 + c, row q
    // grp0: std + h, grp1: min, grp2: max, grp3: mean
    auto stw = [&](int s, short4_t val){
      int k0 = s*64 + cbase;
      int ks = k0>>5, g2=(k0>>3)&3, j0 = cbase&7;
      *reinterpret_cast<short4_t*>(&xl[(((wv*10+ks)*64 + g2*16 + q)<<3) + j0]) = val;
    };
    if (grp==0){
      stw(0, (short4_t){(short)f2bf(sd0),(short)f2bf(sd1),(short)f2bf(sd2),(short)f2bf(sd3)});
      uint2 hu = {0u,0u};
      if (nv) hu = *reinterpret_cast<const uint2*>(hin + (size_t)n*64 + cbase);
      stw(4, (short4_t){(short)(hu.x&0xffffu),(short)(hu.x>>16),(short)(hu.y&0xffffu),(short)(hu.y>>16)});
    } else if (grp==1){
      stw(1, (short4_t){(short)f2bf(mn0),(short)f2bf(mn1),(short)f2bf(mn2),(short)f2bf(mn3)});
    } else if (grp==2){
      stw(2, (short4_t){(short)f2bf(mx0),(short)f2bf(mx1),(short)f2bf(mx2),(short)f2bf(mx3)});
    } else {
      stw(3, (short4_t){(short)f2bf(me0),(short)f2bf(me1),(short)f2bf(me2),(short)f2bf(me3)});
    }
  }
  __syncthreads();

  int r0 = (lane>>4)*4;
  const short8* xw = reinterpret_cast<const short8*>(xl) + wv*10*64 + lane;
  const short8* w1 = reinterpret_cast<const short8*>(w1f) + lane;
  floatx4 acc[4];
  #pragma unroll
  for (int ct=0;ct<4;ct++){ float bb=b1[ct*16+(lane&15)]; acc[ct]=(floatx4){bb,bb,bb,bb}; }
  #pragma unroll
  for (int ks=0; ks<10; ks++){
    short8 a = xw[ks*64];
    #pragma unroll
    for (int ct=0;ct<4;ct++)
      acc[ct] = __builtin_amdgcn_mfma_f32_16x16x32_bf16(a, w1[(ks*4+ct)*64], acc[ct], 0,0,0);
  }
  __syncthreads();   // full fence before overlay of slots 0-1
  #pragma unroll
  for (int ct=0; ct<4; ct++){
    int colk = ct*16 + (lane&15);
    int ks2 = colk>>5, g2=(colk>>3)&3, j2=colk&7;
    #pragma unroll
    for (int j=0;j<4;j++)
      xl[(((wv*10+ks2)*64 + g2*16 + (r0+j))<<3) + j2] = (short)f2bf(fmaxf(acc[ct][j],0.f));
  }
  __syncthreads();

  const short8* w2 = reinterpret_cast<const short8*>(w2f) + lane;
  floatx4 mac[4];
  #pragma unroll
  for (int ct=0;ct<4;ct++){ float bb=b2[ct*16+(lane&15)]; mac[ct]=(floatx4){bb,bb,bb,bb}; }
  #pragma unroll
  for (int ks=0; ks<2; ks++){
    short8 a = xw[ks*64];
    #pragma unroll
    for (int ct=0;ct<4;ct++)
      mac[ct] = __builtin_amdgcn_mfma_f32_16x16x32_bf16(a, w2[(ks*4+ct)*64], mac[ct], 0,0,0);
  }
  #pragma unroll
  for (int ct=0;ct<4;ct++){
    int col = ct*16+(lane&15);
    #pragma unroll
    for (int j=0;j<4;j++){
      int n = n0 + wv*16 + r0 + j;
      if (n < NN){
        float v = mac[ct][j];
        emb[(size_t)n*64+col] = f2bf(v);
        hout[(size_t)n*64+col] = f2bf(fmaxf(v,0.f));
      }
    }
  }
}

// ------------------------- readout kernel -------------------------
// ORIGINAL edge order (no eperm, coalesced out). Layer-1 A-fragments direct
// from gather registers; zero LDS, zero barriers.
__launch_bounds__(256)
__global__ void k_readout(const ushort_t* __restrict__ emb,
                          const int* __restrict__ srcI, const int* __restrict__ dstI,
                          const float* __restrict__ ef,
                          const ushort_t* __restrict__ w1f,
                          const float* __restrict__ b1,
                          const float* __restrict__ w2, const float* __restrict__ b2,
                          float* __restrict__ out){
  int p0 = blockIdx.x*64;
  int tid = threadIdx.x;
  int wv = tid>>6, lane = tid&63;
  int r = lane&15, g = lane>>4;

  int p = p0 + wv*16 + r;
  int sv = srcI[p];
  int dv = dstI[p];
  float2 f = reinterpret_cast<const float2*>(ef)[p];
  unsigned ev = (unsigned)f2bf(f.x) | ((unsigned)f2bf(f.y)<<16);

  short8 v[5];
  #pragma unroll
  for (int ks=0; ks<5; ks++){
    int cc = ks*4 + g;
    short8 x = {0,0,0,0,0,0,0,0};
    if (cc < 16){
      int row = (cc<8)? sv : dv;   // attacker = src first
      x = *reinterpret_cast<const short8*>(emb + (size_t)row*64 + (cc&7)*8);
    } else if (cc == 16){
      x[0] = (short)(ev & 0xffffu); x[1] = (short)(ev >> 16);
    }
    v[ks] = x;
  }

  const short8* w1 = reinterpret_cast<const short8*>(w1f) + lane;
  floatx4 acc[4];
  #pragma unroll
  for (int ct=0;ct<4;ct++){ float bb=b1[ct*16+(lane&15)]; acc[ct]=(floatx4){bb,bb,bb,bb}; }
  #pragma unroll
  for (int ks=0; ks<5; ks++){
    #pragma unroll
    for (int ct=0;ct<4;ct++)
      acc[ct] = __builtin_amdgcn_mfma_f32_16x16x32_bf16(v[ks], w1[(ks*4+ct)*64], acc[ct], 0,0,0);
  }
  float w2v[4];
  #pragma unroll
  for (int ct=0;ct<4;ct++) w2v[ct] = w2[ct*16+(lane&15)];
  float part[4];
  #pragma unroll
  for (int j=0;j<4;j++){
    float pj = 0.f;
    #pragma unroll
    for (int ct=0;ct<4;ct++) pj += fmaxf(acc[ct][j],0.f)*w2v[ct];
    part[j] = pj;
  }
  #pragma unroll
  for (int m=1;m<16;m<<=1){
    #pragma unroll
    for (int j=0;j<4;j++) part[j] += __shfl_xor(part[j], m, 64);
  }
  if ((lane&15)==0){
    int r0 = (lane>>4)*4;
    float bb = b2[0];
    #pragma unroll
    for (int j=0;j<4;j++)
      out[p0 + wv*16 + r0 + j] = part[j] + bb;
  }
}

// ------------------------- launcher -------------------------
extern "C" void kernel_launch(void* const* d_in, const int* in_sizes, int n_in,
                              void* d_out, int out_size, void* d_ws, size_t ws_size,
                              hipStream_t stream){
  const float* nf    = (const float*)d_in[0];
  const float* ef    = (const float*)d_in[1];
  const float* initW = (const float*)d_in[2];
  const float* initb = (const float*)d_in[3];
  const float* msgW1 = (const float*)d_in[4];
  const float* msgb1 = (const float*)d_in[5];
  const float* msgW2 = (const float*)d_in[6];
  const float* msgb2 = (const float*)d_in[7];
  const float* updW1 = (const float*)d_in[8];
  const float* updb1 = (const float*)d_in[9];
  const float* updW2 = (const float*)d_in[10];
  const float* updb2 = (const float*)d_in[11];
  const float* roW1  = (const float*)d_in[12];
  const float* rob1  = (const float*)d_in[13];
  const float* roW2  = (const float*)d_in[14];
  const float* rob2  = (const float*)d_in[15];
  const int*   eidx  = (const int*)d_in[16];
  const int* srcI = eidx;
  const int* dstI = eidx + NE;
  float* out = (float*)d_out;

  char* base = (char*)d_ws; size_t off = 0;
  auto alloc = [&](size_t b)->char*{ char* p = base + off; off = (off + b + 255) & ~(size_t)255; return p; };
  int* cnt    = (int*)alloc((size_t)NN*4);
  int* fill   = (int*)alloc((size_t)NN*4);
  int* rowptr = (int*)alloc((size_t)(NN+1)*4);
  int* bsum   = (int*)alloc(512*4);
  int4* edges = (int4*)alloc((size_t)NE*16);
  ushort_t* hA  = (ushort_t*)alloc((size_t)NN*64*2);
  ushort_t* hB  = (ushort_t*)alloc((size_t)NN*64*2);
  ushort_t* emb = (ushort_t*)alloc((size_t)NN*64*2);
  ushort_t* m_s = (ushort_t*)alloc((size_t)NE*64*2);
  ushort_t* msgW1f = (ushort_t*)alloc(5*2048*2);
  ushort_t* msgW2f = (ushort_t*)alloc(2*2048*2);
  ushort_t* updW1f = (ushort_t*)alloc(10*2048*2);
  ushort_t* updW2f = (ushort_t*)alloc(2*2048*2);
  ushort_t* roW1f  = (ushort_t*)alloc(5*2048*2);
  (void)ws_size; (void)in_sizes; (void)n_in; (void)out_size;

  hipMemsetAsync(cnt, 0, (size_t)NN*4, stream);
  hipMemsetAsync(fill, 0, (size_t)NN*4, stream);
  int nb = (NN+255)/256;
  k_count<<<(NE+255)/256,256,0,stream>>>(dstI,cnt);
  k_scan1<<<nb,256,0,stream>>>(cnt,bsum);
  k_scan2<<<1,512,0,stream>>>(bsum,nb);
  k_scan3<<<nb,256,0,stream>>>(cnt,bsum,rowptr);
  k_scatter<<<(NE+255)/256,256,0,stream>>>(srcI,dstI,ef,rowptr,fill,edges);
  k_wprep<<<(5*2048+255)/256,256,0,stream>>>(msgW1,msgW1f,130,5*2048);
  k_wprep<<<(2*2048+255)/256,256,0,stream>>>(msgW2,msgW2f,64,2*2048);
  k_wprep<<<(10*2048+255)/256,256,0,stream>>>(updW1,updW1f,320,10*2048);
  k_wprep<<<(2*2048+255)/256,256,0,stream>>>(updW2,updW2f,64,2*2048);
  k_wprep<<<(5*2048+255)/256,256,0,stream>>>(roW1,roW1f,130,5*2048);
  k_init<<<(NN*64+255)/256,256,0,stream>>>(nf,initW,initb,hA,emb);

  for (int it=0; it<ITERS; it++){
    const ushort_t* hin = (it&1)? hB : hA;
    ushort_t* hout      = (it&1)? hA : hB;
    k_edge<<<NE/64,256,0,stream>>>(hin,edges,msgW1f,msgW2f,msgb1,msgb2,m_s);
    k_update<<<(NN+63)/64,256,0,stream>>>(m_s,rowptr,hin,updW1f,updW2f,updb1,updb2,emb,hout);
  }
  k_readout<<<NE/64,256,0,stream>>>(emb,srcI,dstI,ef,roW1f,rob1,roW2,rob2,out);
}